// Round 3
// baseline (142.878 us; speedup 1.0000x reference)
//
#include <hip/hip_runtime.h>
#include <hip/hip_bf16.h>

typedef _Float16 f16x8 __attribute__((ext_vector_type(8)));
typedef float f32x4 __attribute__((ext_vector_type(4)));

#define T_DIM 2048
#define H_DIM 2048
#define N_HEADS 16
#define DH 128
#define KBLK 50
#define NBLK 41
#define NEGV (-1.0e9f)
#define QSCALE 0.08838834764831845f  // 128^-0.5

__device__ __forceinline__ void gl_lds16(const void* g, void* l) {
    __builtin_amdgcn_global_load_lds(
        (const __attribute__((address_space(1))) void*)g,
        (__attribute__((address_space(3))) void*)l, 16, 0, 0);
}

// ---- fused prep: z<4 -> transpose weight fp32->fp16; z==4 -> convert x fp32->fp16 ----
__global__ __launch_bounds__(256) void prep_kernel(const float* __restrict__ x,
                                                   const float* __restrict__ Wq,
                                                   const float* __restrict__ Wk,
                                                   const float* __restrict__ Wv,
                                                   const float* __restrict__ Wo,
                                                   _Float16* __restrict__ xb,
                                                   _Float16* __restrict__ WT,
                                                   _Float16* __restrict__ WoT) {
    __shared__ float tile[32][33];
    int z = blockIdx.z;
    const float* src = (z == 0) ? Wq : (z == 1) ? Wk : (z == 2) ? Wv : (z == 3) ? Wo : x;
    _Float16* dst = (z == 3) ? WoT : (z == 4) ? xb : (WT + (size_t)z * T_DIM * H_DIM);
    int bx = blockIdx.x * 32, by = blockIdx.y * 32;
    int tx = threadIdx.x, ty = threadIdx.y;  // 32 x 8
    if (z == 4) {
#pragma unroll
        for (int i = 0; i < 4; i++) {
            int r = by + ty + i * 8;
            dst[(size_t)r * H_DIM + bx + tx] = (_Float16)src[(size_t)r * H_DIM + bx + tx];
        }
    } else {
#pragma unroll
        for (int i = 0; i < 4; i++)
            tile[ty + i * 8][tx] = src[(size_t)(by + ty + i * 8) * H_DIM + bx + tx];
        __syncthreads();
#pragma unroll
        for (int i = 0; i < 4; i++)
            dst[(size_t)(bx + ty + i * 8) * H_DIM + by + tx] = (_Float16)tile[tx][ty + i * 8];
    }
}

// ---------------- GEMM: C = A(MxK f16 rm) * B, B given as BT (NxK f16 rm) ----------------
// BM=128 x BN tile, BK=32, 256 threads = 4 waves. TRIPLE-buffered LDS, staging 2 K-tiles
// ahead via global_load_lds; ONE raw s_barrier + counted s_waitcnt vmcnt(L) per K-step
// (never drains the load queue in the main loop -- T4).
// Safety: (a) vmcnt(L)+barrier => tile t fully landed (all waves) before its ds_reads;
// (b) lgkmcnt(0) before barrier => all waves' iter t-1 LDS reads done before stage(t+2)
//     overwrites buf[(t+2)%3] (= buffer read in iter t-1);
// (c) last TWO tiles peeled with vmcnt(0) (uniform vmcnt(L) would admit unlanded tail).
// MODE 0: write q/k/v fp16 [tensor][e][t][f], scale q by QSCALE. MODE 1: write fp32 rm.
template <int MODE, int BN>
__global__ __launch_bounds__(256) void gemm_kernel(const _Float16* __restrict__ A,
                                                   const _Float16* __restrict__ BT,
                                                   void* __restrict__ Cout,
                                                   int M, int N, int K) {
    constexpr int BM = 128, BK = 32;
    constexpr int NB = BN / 32;              // N-frags per wave
    constexpr int AL = (BM * BK / 8) / 256;  // A gl_lds per thread per tile (2)
    constexpr int BL = (BN * BK / 8) / 256;  // B gl_lds per thread per tile (2 or 1)
    __shared__ _Float16 As[3][BM * BK];
    __shared__ _Float16 Bs[3][BN * BK];
    int tid = threadIdx.x;
    int lane = tid & 63, wave = tid >> 6;
    int bm = blockIdx.y * BM, bn = blockIdx.x * BN;
    int wr = (wave >> 1) * 64, wc = (wave & 1) * (BN / 2);
    int cb = lane & 15, hi = lane >> 4;

    f32x4 acc[4][NB];
#pragma unroll
    for (int m = 0; m < 4; m++)
#pragma unroll
        for (int n = 0; n < NB; n++) acc[m][n] = (f32x4){0.f, 0.f, 0.f, 0.f};

    auto stage = [&](int t, int buf) {
        int k0 = t * BK;
#pragma unroll
        for (int r = 0; r < AL; r++) {
            int c = tid + r * 256;
            gl_lds16(&A[(size_t)(bm + (c >> 2)) * K + k0 + (c & 3) * 8], &As[buf][c * 8]);
        }
#pragma unroll
        for (int r = 0; r < BL; r++) {
            int c = tid + r * 256;
            gl_lds16(&BT[(size_t)(bn + (c >> 2)) * K + k0 + (c & 3) * 8], &Bs[buf][c * 8]);
        }
    };

    auto compute = [&](int cur) {
        f16x8 a[4], b[NB];
#pragma unroll
        for (int m = 0; m < 4; m++)
            a[m] = *(const f16x8*)&As[cur][(wr + m * 16 + cb) * BK + hi * 8];
#pragma unroll
        for (int n = 0; n < NB; n++)
            b[n] = *(const f16x8*)&Bs[cur][(wc + n * 16 + cb) * BK + hi * 8];
#pragma unroll
        for (int m = 0; m < 4; m++)
#pragma unroll
            for (int n = 0; n < NB; n++)
                acc[m][n] = __builtin_amdgcn_mfma_f32_16x16x32_f16(a[m], b[n], acc[m][n], 0, 0, 0);
    };

    const int NT = K / BK;
    stage(0, 0);
    stage(1, 1);

    int cur = 0, nx2 = 2;  // buf of tile t, buf of tile t+2
    for (int t = 0; t < NT - 2; t++) {
        if constexpr (AL + BL == 4)
            asm volatile("s_waitcnt vmcnt(4) lgkmcnt(0)" ::: "memory");
        else
            asm volatile("s_waitcnt vmcnt(3) lgkmcnt(0)" ::: "memory");
        __builtin_amdgcn_s_barrier();
        __builtin_amdgcn_sched_barrier(0);
        stage(t + 2, nx2);
        compute(cur);
        cur = (cur == 2) ? 0 : cur + 1;
        nx2 = (nx2 == 2) ? 0 : nx2 + 1;
    }
    // tile NT-2: its loads may be the only outstanding ones -> must drain
    asm volatile("s_waitcnt vmcnt(0) lgkmcnt(0)" ::: "memory");
    __builtin_amdgcn_s_barrier();
    __builtin_amdgcn_sched_barrier(0);
    compute(cur);
    cur = (cur == 2) ? 0 : cur + 1;
    // tile NT-1 (already landed by the vmcnt(0) above; barrier keeps wave sync)
    __builtin_amdgcn_s_barrier();
    __builtin_amdgcn_sched_barrier(0);
    compute(cur);

    if (MODE == 0) {
        _Float16* qkv = (_Float16*)Cout;
#pragma unroll
        for (int m = 0; m < 4; m++) {
#pragma unroll
            for (int n = 0; n < NB; n++) {
                int gn = bn + wc + n * 16 + cb;
                int tensor = gn >> 11;
                int ef = gn & 2047;
                int e = ef >> 7, f = ef & 127;
                float scale = (tensor == 0) ? QSCALE : 1.0f;
                _Float16* base = qkv + (size_t)tensor * (T_DIM * H_DIM) + (size_t)e * (T_DIM * DH) + f;
#pragma unroll
                for (int r = 0; r < 4; r++) {
                    int gm = bm + wr + m * 16 + hi * 4 + r;
                    base[(size_t)gm * DH] = (_Float16)(acc[m][n][r] * scale);
                }
            }
        }
    } else {
        float* C = (float*)Cout;
#pragma unroll
        for (int m = 0; m < 4; m++)
#pragma unroll
            for (int n = 0; n < NB; n++) {
                int gn = bn + wc + n * 16 + cb;
#pragma unroll
                for (int r = 0; r < 4; r++) {
                    int gm = bm + wr + m * 16 + hi * 4 + r;
                    C[(size_t)gm * N + gn] = acc[m][n][r];
                }
            }
    }
}

// ---------------- per-(block,head) attention ----------------
// grid = 41*16 blocks, 256 threads (4 waves). Wave w owns query rows [w*16, w*16+16).
__global__ __launch_bounds__(256) void attn_kernel(const _Float16* __restrict__ qkvb,
                                                   const float* __restrict__ bias,
                                                   const float* __restrict__ mask,
                                                   _Float16* __restrict__ aout) {
    int bid = blockIdx.x;
    int n = bid >> 4, e = bid & 15;
    int t0 = n * KBLK;
    int valid = (T_DIM - t0 < KBLK) ? (T_DIM - t0) : KBLK;

    __shared__ _Float16 Qs[64 * 136];
    __shared__ _Float16 Ks[64 * 136];
    __shared__ _Float16 VTs[128 * 72];
    __shared__ _Float16 Ps[64 * 72];
    __shared__ float maskv[64];

    int tid = threadIdx.x;
    int lane = tid & 63, wave = tid >> 6;
    const _Float16* qp = qkvb + (size_t)e * (T_DIM * DH);
    const _Float16* kp = qkvb + (size_t)(T_DIM * H_DIM) + (size_t)e * (T_DIM * DH);
    const _Float16* vp = qkvb + (size_t)2 * (T_DIM * H_DIM) + (size_t)e * (T_DIM * DH);

    // stage Q, K tiles (zero-padded to 64 rows), vectorized
#pragma unroll
    for (int i = 0; i < 4; i++) {
        int c = tid + i * 256;
        int r = c >> 4, c8 = c & 15;
        uint4 z = {0u, 0u, 0u, 0u};
        uint4 vq = z, vk = z;
        if (r < valid) {
            vq = *(const uint4*)&qp[(size_t)(t0 + r) * DH + c8 * 8];
            vk = *(const uint4*)&kp[(size_t)(t0 + r) * DH + c8 * 8];
        }
        *(uint4*)&Qs[r * 136 + c8 * 8] = vq;
        *(uint4*)&Ks[r * 136 + c8 * 8] = vk;
    }
    // stage V transposed, vectorized: 16B loads, lane-consecutive-row LDS writes
#pragma unroll
    for (int i = 0; i < 4; i++) {
        int c = tid + i * 256;
        int r = c & 63;
        int f0 = (c >> 6) * 8;
        uint4 v = {0u, 0u, 0u, 0u};
        if (r < valid) v = *(const uint4*)&vp[(size_t)(t0 + r) * DH + f0];
        _Float16 tmp[8];
        *(uint4*)tmp = v;
#pragma unroll
        for (int j = 0; j < 8; j++) VTs[(f0 + j) * 72 + r] = tmp[j];
    }
    if (tid < 64) maskv[tid] = (tid < valid) ? mask[t0 + tid] : NEGV;
    __syncthreads();

    int qr0 = wave * 16;
    int cb = lane & 15, hi = lane >> 4;

    // S = Q K^T  (64 padded rows x 64 padded cols), wave handles 16 q-rows
    f16x8 aq[4];
#pragma unroll
    for (int ks = 0; ks < 4; ks++)
        aq[ks] = *(const f16x8*)&Qs[(qr0 + cb) * 136 + ks * 32 + hi * 8];
    f32x4 s[4];
#pragma unroll
    for (int kt = 0; kt < 4; kt++) s[kt] = (f32x4){0.f, 0.f, 0.f, 0.f};
#pragma unroll
    for (int kt = 0; kt < 4; kt++)
#pragma unroll
        for (int ks = 0; ks < 4; ks++) {
            f16x8 bk = *(const f16x8*)&Ks[(kt * 16 + cb) * 136 + ks * 32 + hi * 8];
            s[kt] = __builtin_amdgcn_mfma_f32_16x16x32_f16(aq[ks], bk, s[kt], 0, 0, 0);
        }

    // bias + mask + softmax (row-wise over the 64 padded cols; pads forced to NEG)
#pragma unroll
    for (int r = 0; r < 4; r++) {
        int rl = qr0 + hi * 4 + r;
        int qi = t0 + rl;
        float mq = maskv[rl];
        float lg[4];
        float mx = -3.4e38f;
#pragma unroll
        for (int kt = 0; kt < 4; kt++) {
            int cl = kt * 16 + cb, ki = t0 + cl;
            float bg = (qi < T_DIM && ki < T_DIM)
                           ? bias[((size_t)e * T_DIM + qi) * T_DIM + ki] : 0.f;
            float pr = mq * maskv[cl];
            float v = s[kt][r] + bg + (pr > 0.f ? 0.f : NEGV);
            lg[kt] = v;
            mx = fmaxf(mx, v);
        }
#pragma unroll
        for (int off = 8; off; off >>= 1) mx = fmaxf(mx, __shfl_xor(mx, off));
        float sum = 0.f;
#pragma unroll
        for (int kt = 0; kt < 4; kt++) {
            float pe = __expf(lg[kt] - mx);
            lg[kt] = pe;
            sum += pe;
        }
#pragma unroll
        for (int off = 8; off; off >>= 1) sum += __shfl_xor(sum, off);
        float inv = 1.f / sum;
#pragma unroll
        for (int kt = 0; kt < 4; kt++)
            Ps[rl * 72 + kt * 16 + cb] = (_Float16)(lg[kt] * inv);
    }
    __syncthreads();

    // O = P V   (reduction over 64 padded keys), write fp16 [t][e*128+f]
    f16x8 pa[2];
#pragma unroll
    for (int ks = 0; ks < 2; ks++)
        pa[ks] = *(const f16x8*)&Ps[(qr0 + cb) * 72 + ks * 32 + hi * 8];
#pragma unroll
    for (int ft = 0; ft < 8; ft++) {
        f32x4 o = (f32x4){0.f, 0.f, 0.f, 0.f};
#pragma unroll
        for (int ks = 0; ks < 2; ks++) {
            f16x8 bv = *(const f16x8*)&VTs[(ft * 16 + cb) * 72 + ks * 32 + hi * 8];
            o = __builtin_amdgcn_mfma_f32_16x16x32_f16(pa[ks], bv, o, 0, 0, 0);
        }
#pragma unroll
        for (int r = 0; r < 4; r++) {
            int rl = qr0 + hi * 4 + r;
            if (rl < valid)
                aout[(size_t)(t0 + rl) * H_DIM + e * DH + ft * 16 + cb] = (_Float16)o[r];
        }
    }
}

extern "C" void kernel_launch(void* const* d_in, const int* in_sizes, int n_in,
                              void* d_out, int out_size, void* d_ws, size_t ws_size,
                              hipStream_t stream) {
    const float* x    = (const float*)d_in[0];
    const float* mask = (const float*)d_in[1];
    const float* bias = (const float*)d_in[2];
    const float* Wq   = (const float*)d_in[3];
    const float* Wk   = (const float*)d_in[4];
    const float* Wv   = (const float*)d_in[5];
    const float* Wo   = (const float*)d_in[6];
    float* out = (float*)d_out;

    // workspace layout (fp16): xb[4M] | WT[12M] | WoT[4M] | qkv[12M] | aout[4M]  = 72MB
    _Float16* xb   = (_Float16*)d_ws;
    _Float16* WT   = xb + (size_t)T_DIM * H_DIM;
    _Float16* WoT  = WT + (size_t)3 * T_DIM * H_DIM;
    _Float16* qkvb = WoT + (size_t)T_DIM * H_DIM;
    _Float16* aout = qkvb + (size_t)3 * T_DIM * H_DIM;

    prep_kernel<<<dim3(64, 64, 5), dim3(32, 8), 0, stream>>>(x, Wq, Wk, Wv, Wo, xb, WT, WoT);

    // fused QKV projection: A = xb (2048x2048), BT = WT (6144x2048)
    gemm_kernel<0, 128><<<dim3(6144 / 128, T_DIM / 128), 256, 0, stream>>>(
        xb, WT, (void*)qkvb, T_DIM, 3 * H_DIM, H_DIM);

    attn_kernel<<<NBLK * N_HEADS, 256, 0, stream>>>(qkvb, bias, mask, aout);

    // output projection: A = aout (2048x2048), BT = WoT (2048x2048), C = fp32 out
    gemm_kernel<1, 64><<<dim3(H_DIM / 64, T_DIM / 128), 256, 0, stream>>>(
        aout, WoT, (void*)out, T_DIM, H_DIM, H_DIM);
}

// Round 5
// 142.669 us; speedup vs baseline: 1.0015x; 1.0015x over previous
//
#include <hip/hip_runtime.h>
#include <hip/hip_bf16.h>

typedef _Float16 f16x8 __attribute__((ext_vector_type(8)));
typedef float f32x4 __attribute__((ext_vector_type(4)));

#define T_DIM 2048
#define H_DIM 2048
#define N_HEADS 16
#define DH 128
#define KBLK 50
#define NBLK 41
#define NEGV (-1.0e9f)
#define QSCALE 0.08838834764831845f  // 128^-0.5

__device__ __forceinline__ void gl_lds16(const void* g, void* l) {
    __builtin_amdgcn_global_load_lds(
        (const __attribute__((address_space(1))) void*)g,
        (__attribute__((address_space(3))) void*)l, 16, 0, 0);
}

// ---- fused prep: z<4 -> transpose weight fp32->fp16; z==4 -> convert x fp32->fp16 ----
__global__ __launch_bounds__(256) void prep_kernel(const float* __restrict__ x,
                                                   const float* __restrict__ Wq,
                                                   const float* __restrict__ Wk,
                                                   const float* __restrict__ Wv,
                                                   const float* __restrict__ Wo,
                                                   _Float16* __restrict__ xb,
                                                   _Float16* __restrict__ WT,
                                                   _Float16* __restrict__ WoT) {
    __shared__ float tile[32][33];
    int z = blockIdx.z;
    const float* src = (z == 0) ? Wq : (z == 1) ? Wk : (z == 2) ? Wv : (z == 3) ? Wo : x;
    _Float16* dst = (z == 3) ? WoT : (z == 4) ? xb : (WT + (size_t)z * T_DIM * H_DIM);
    int bx = blockIdx.x * 32, by = blockIdx.y * 32;
    int tx = threadIdx.x, ty = threadIdx.y;  // 32 x 8
    if (z == 4) {
#pragma unroll
        for (int i = 0; i < 4; i++) {
            int r = by + ty + i * 8;
            dst[(size_t)r * H_DIM + bx + tx] = (_Float16)src[(size_t)r * H_DIM + bx + tx];
        }
    } else {
#pragma unroll
        for (int i = 0; i < 4; i++)
            tile[ty + i * 8][tx] = src[(size_t)(by + ty + i * 8) * H_DIM + bx + tx];
        __syncthreads();
#pragma unroll
        for (int i = 0; i < 4; i++)
            dst[(size_t)(bx + ty + i * 8) * H_DIM + by + tx] = (_Float16)tile[tx][ty + i * 8];
    }
}

// =============== 256x256 8-phase-style GEMM (QKV projection) =================
// BM=BN=256, BK=64, 512 threads = 8 waves (2M x 4N), per-wave C = 128x64.
// 4 phases per K-tile, 16 MFMA each. LDS 128KB double-buffered, T2 XOR-swizzle
// (linear gl_lds dest + pre-swizzled global source + swizzled ds_read).
// Sync ledger:
//  - reads of tile t happen only in ph0/ph1; each wave drains lgkmcnt(0) before its
//    MFMA, hence before ph1's end barrier => buffer free for writes from ph2 on.
//  - pieces of tile t+1 staged at (t-1,ph2),(t-1,ph3),(t,ph0),(t,ph1)  [1 piece/phase]
//    (targets buf[~t&1], free since (t-1,ph1)-end).
//  - vmcnt(4) at (t,ph3) before barrier => all 4 pieces of tile t+1 landed in THIS
//    wave; barrier makes it block-wide before (t+1,ph0)'s ds_reads. 2 pieces stay
//    in flight (never drains in steady state). Tail: vmcnt(0) at t=NT-2.
__global__ __launch_bounds__(512, 2) void gemm256_kernel(const _Float16* __restrict__ A,
                                                         const _Float16* __restrict__ BT,
                                                         _Float16* __restrict__ qkv,
                                                         int K, int NXB) {
    __shared__ _Float16 sA[2][16384];
    __shared__ _Float16 sB[2][16384];

    int tid = threadIdx.x;
    int lane = tid & 63, wave = tid >> 6;
    int wm = wave >> 2, wn = wave & 3;
    int cb = lane & 15, hi = lane >> 4;

    // XCD swizzle: 192 = 8 XCDs x 24; each XCD owns one full M-row of tiles
    int bid = blockIdx.x;
    int swz = (bid & 7) * NXB + (bid >> 3);
    int by = swz / NXB, bx = swz - by * NXB;
    int bm = by * 256, bn = bx * 256;

    f32x4 acc[8][4];
#pragma unroll
    for (int m = 0; m < 8; m++)
#pragma unroll
        for (int n = 0; n < 4; n++) acc[m][n] = (f32x4){0.f, 0.f, 0.f, 0.f};

    // stage one half-tile (piece): p=0/1 -> A rows 0-127/128-255; p=2/3 -> B ditto.
    // 512 thr x 2 chunks of 16B = 16KB. Source col pre-swizzled so that reading
    // LDS at byte (row*128 + col) ^ ((row&7)<<4) yields logical (row, col).
    auto stageP = [&](int t, int p) {
        int buf = t & 1, k0 = t << 6;
        const _Float16* src = (p < 2) ? A + (size_t)(bm + ((p & 1) << 7)) * K + k0
                                      : BT + (size_t)(bn + ((p & 1) << 7)) * K + k0;
        _Float16* dst = ((p < 2) ? (buf ? sA[1] : sA[0]) : (buf ? sB[1] : sB[0])) + ((p & 1) << 13);
#pragma unroll
        for (int l = 0; l < 2; l++) {
            int c = l * 512 + tid;
            int rp = c >> 3, cc = c & 7;
            int col = (cc ^ (rp & 7)) << 3;  // f16 units, pre-swizzled
            gl_lds16(src + (size_t)rp * K + col, dst + c * 8);
        }
    };

    f16x8 a_lo[4][2], a_hi[4][2], b_lo[2][2], b_hi[2][2];

    // prologue: tile0 all 4 pieces + tile1 pieces 0,1; confirm tile0 (2 pieces in flight)
    stageP(0, 0); stageP(0, 1); stageP(0, 2); stageP(0, 3);
    stageP(1, 0); stageP(1, 1);
    asm volatile("s_waitcnt vmcnt(4)" ::: "memory");
    __builtin_amdgcn_s_barrier();

    const int NT = K >> 6;
    for (int t = 0; t < NT; t++) {
        int buf = t & 1;
        const char* bA = (const char*)(buf ? sA[1] : sA[0]);
        const char* bB = (const char*)(buf ? sB[1] : sB[0]);
        // ---- ph0: read a_lo(8) + b_lo(4); stage P2(t+1); MFMA Mlo x Nlo ----
#pragma unroll
        for (int m = 0; m < 4; m++) {
            int ra = wm * 128 + m * 16 + cb;
#pragma unroll
            for (int ks = 0; ks < 2; ks++)
                a_lo[m][ks] = *(const f16x8*)(bA + (ra << 7) +
                                              ((ks * 64 + hi * 16) ^ ((ra & 7) << 4)));
        }
#pragma unroll
        for (int n = 0; n < 2; n++) {
            int rb = wn * 64 + n * 16 + cb;
#pragma unroll
            for (int ks = 0; ks < 2; ks++)
                b_lo[n][ks] = *(const f16x8*)(bB + (rb << 7) +
                                              ((ks * 64 + hi * 16) ^ ((rb & 7) << 4)));
        }
        if (t + 1 < NT) stageP(t + 1, 2);
        __builtin_amdgcn_s_barrier();
        asm volatile("s_waitcnt lgkmcnt(0)" ::: "memory");
        __builtin_amdgcn_s_setprio(1);
#pragma unroll
        for (int m = 0; m < 4; m++)
#pragma unroll
            for (int n = 0; n < 2; n++)
#pragma unroll
                for (int ks = 0; ks < 2; ks++)
                    acc[m][n] = __builtin_amdgcn_mfma_f32_16x16x32_f16(a_lo[m][ks], b_lo[n][ks], acc[m][n], 0, 0, 0);
        __builtin_amdgcn_s_setprio(0);
        __builtin_amdgcn_s_barrier();

        // ---- ph1: read a_hi(8) + b_hi(4); stage P3(t+1); MFMA Mhi x Nhi ----
#pragma unroll
        for (int m = 0; m < 4; m++) {
            int ra = wm * 128 + 64 + m * 16 + cb;
#pragma unroll
            for (int ks = 0; ks < 2; ks++)
                a_hi[m][ks] = *(const f16x8*)(bA + (ra << 7) +
                                              ((ks * 64 + hi * 16) ^ ((ra & 7) << 4)));
        }
#pragma unroll
        for (int n = 0; n < 2; n++) {
            int rb = wn * 64 + 32 + n * 16 + cb;
#pragma unroll
            for (int ks = 0; ks < 2; ks++)
                b_hi[n][ks] = *(const f16x8*)(bB + (rb << 7) +
                                              ((ks * 64 + hi * 16) ^ ((rb & 7) << 4)));
        }
        if (t + 1 < NT) stageP(t + 1, 3);
        __builtin_amdgcn_s_barrier();
        asm volatile("s_waitcnt lgkmcnt(0)" ::: "memory");
        __builtin_amdgcn_s_setprio(1);
#pragma unroll
        for (int m = 0; m < 4; m++)
#pragma unroll
            for (int n = 0; n < 2; n++)
#pragma unroll
                for (int ks = 0; ks < 2; ks++)
                    acc[4 + m][2 + n] = __builtin_amdgcn_mfma_f32_16x16x32_f16(a_hi[m][ks], b_hi[n][ks], acc[4 + m][2 + n], 0, 0, 0);
        __builtin_amdgcn_s_setprio(0);
        __builtin_amdgcn_s_barrier();

        // ---- ph2: stage P0(t+2); MFMA Mlo x Nhi ----
        if (t + 2 < NT) stageP(t + 2, 0);
        __builtin_amdgcn_s_barrier();
        __builtin_amdgcn_s_setprio(1);
#pragma unroll
        for (int m = 0; m < 4; m++)
#pragma unroll
            for (int n = 0; n < 2; n++)
#pragma unroll
                for (int ks = 0; ks < 2; ks++)
                    acc[m][2 + n] = __builtin_amdgcn_mfma_f32_16x16x32_f16(a_lo[m][ks], b_hi[n][ks], acc[m][2 + n], 0, 0, 0);
        __builtin_amdgcn_s_setprio(0);
        __builtin_amdgcn_s_barrier();

        // ---- ph3: stage P1(t+2); vmcnt confirms tile t+1; MFMA Mhi x Nlo ----
        if (t + 2 < NT) stageP(t + 2, 1);
        if (t < NT - 2)
            asm volatile("s_waitcnt vmcnt(4)" ::: "memory");
        else if (t == NT - 2)
            asm volatile("s_waitcnt vmcnt(0)" ::: "memory");
        __builtin_amdgcn_s_barrier();
        __builtin_amdgcn_s_setprio(1);
#pragma unroll
        for (int m = 0; m < 4; m++)
#pragma unroll
            for (int n = 0; n < 2; n++)
#pragma unroll
                for (int ks = 0; ks < 2; ks++)
                    acc[4 + m][n] = __builtin_amdgcn_mfma_f32_16x16x32_f16(a_hi[m][ks], b_lo[n][ks], acc[4 + m][n], 0, 0, 0);
        __builtin_amdgcn_s_setprio(0);
        __builtin_amdgcn_s_barrier();
    }

    // epilogue: scatter to q/k/v fp16 [tensor][e][t][f], scale q by QSCALE
#pragma unroll
    for (int m = 0; m < 8; m++) {
#pragma unroll
        for (int n = 0; n < 4; n++) {
            int gn = bn + wn * 64 + ((n & 1) * 16) + ((n >> 1) * 32) + cb;
            int tensor = gn >> 11;
            int ef = gn & 2047;
            int e = ef >> 7, f = ef & 127;
            float scale = (tensor == 0) ? QSCALE : 1.0f;
            _Float16* base = qkv + (size_t)tensor * (T_DIM * H_DIM) + (size_t)e * (T_DIM * DH) + f;
#pragma unroll
            for (int r = 0; r < 4; r++) {
                int gm = bm + wm * 128 + ((m & 3) * 16) + ((m >> 2) * 64) + hi * 4 + r;
                base[(size_t)gm * DH] = (_Float16)(acc[m][n][r] * scale);
            }
        }
    }
}

// ---------------- 128-tile GEMM (output projection), round-3 structure ----------------
template <int MODE, int BN>
__global__ __launch_bounds__(256) void gemm_kernel(const _Float16* __restrict__ A,
                                                   const _Float16* __restrict__ BT,
                                                   void* __restrict__ Cout,
                                                   int M, int N, int K) {
    constexpr int BM = 128, BK = 32;
    constexpr int NB = BN / 32;
    constexpr int AL = (BM * BK / 8) / 256;
    constexpr int BL = (BN * BK / 8) / 256;
    __shared__ _Float16 As[3][BM * BK];
    __shared__ _Float16 Bs[3][BN * BK];
    int tid = threadIdx.x;
    int lane = tid & 63, wave = tid >> 6;
    int bm = blockIdx.y * BM, bn = blockIdx.x * BN;
    int wr = (wave >> 1) * 64, wc = (wave & 1) * (BN / 2);
    int cb = lane & 15, hi = lane >> 4;

    f32x4 acc[4][NB];
#pragma unroll
    for (int m = 0; m < 4; m++)
#pragma unroll
        for (int n = 0; n < NB; n++) acc[m][n] = (f32x4){0.f, 0.f, 0.f, 0.f};

    auto stage = [&](int t, int buf) {
        int k0 = t * BK;
#pragma unroll
        for (int r = 0; r < AL; r++) {
            int c = tid + r * 256;
            gl_lds16(&A[(size_t)(bm + (c >> 2)) * K + k0 + (c & 3) * 8], &As[buf][c * 8]);
        }
#pragma unroll
        for (int r = 0; r < BL; r++) {
            int c = tid + r * 256;
            gl_lds16(&BT[(size_t)(bn + (c >> 2)) * K + k0 + (c & 3) * 8], &Bs[buf][c * 8]);
        }
    };

    auto compute = [&](int cur) {
        f16x8 a[4], b[NB];
#pragma unroll
        for (int m = 0; m < 4; m++)
            a[m] = *(const f16x8*)&As[cur][(wr + m * 16 + cb) * BK + hi * 8];
#pragma unroll
        for (int n = 0; n < NB; n++)
            b[n] = *(const f16x8*)&Bs[cur][(wc + n * 16 + cb) * BK + hi * 8];
#pragma unroll
        for (int m = 0; m < 4; m++)
#pragma unroll
            for (int n = 0; n < NB; n++)
                acc[m][n] = __builtin_amdgcn_mfma_f32_16x16x32_f16(a[m], b[n], acc[m][n], 0, 0, 0);
    };

    const int NT = K / BK;
    stage(0, 0);
    stage(1, 1);

    int cur = 0, nx2 = 2;
    for (int t = 0; t < NT - 2; t++) {
        if constexpr (AL + BL == 4)
            asm volatile("s_waitcnt vmcnt(4) lgkmcnt(0)" ::: "memory");
        else
            asm volatile("s_waitcnt vmcnt(3) lgkmcnt(0)" ::: "memory");
        __builtin_amdgcn_s_barrier();
        __builtin_amdgcn_sched_barrier(0);
        stage(t + 2, nx2);
        compute(cur);
        cur = (cur == 2) ? 0 : cur + 1;
        nx2 = (nx2 == 2) ? 0 : nx2 + 1;
    }
    asm volatile("s_waitcnt vmcnt(0) lgkmcnt(0)" ::: "memory");
    __builtin_amdgcn_s_barrier();
    __builtin_amdgcn_sched_barrier(0);
    compute(cur);
    cur = (cur == 2) ? 0 : cur + 1;
    __builtin_amdgcn_s_barrier();
    __builtin_amdgcn_sched_barrier(0);
    compute(cur);

    if (MODE == 0) {
        _Float16* qkv = (_Float16*)Cout;
#pragma unroll
        for (int m = 0; m < 4; m++) {
#pragma unroll
            for (int n = 0; n < NB; n++) {
                int gn = bn + wc + n * 16 + cb;
                int tensor = gn >> 11;
                int ef = gn & 2047;
                int e = ef >> 7, f = ef & 127;
                float scale = (tensor == 0) ? QSCALE : 1.0f;
                _Float16* base = qkv + (size_t)tensor * (T_DIM * H_DIM) + (size_t)e * (T_DIM * DH) + f;
#pragma unroll
                for (int r = 0; r < 4; r++) {
                    int gm = bm + wr + m * 16 + hi * 4 + r;
                    base[(size_t)gm * DH] = (_Float16)(acc[m][n][r] * scale);
                }
            }
        }
    } else {
        float* C = (float*)Cout;
#pragma unroll
        for (int m = 0; m < 4; m++)
#pragma unroll
            for (int n = 0; n < NB; n++) {
                int gn = bn + wc + n * 16 + cb;
#pragma unroll
                for (int r = 0; r < 4; r++) {
                    int gm = bm + wr + m * 16 + hi * 4 + r;
                    C[(size_t)gm * N + gn] = acc[m][n][r];
                }
            }
    }
}

// ---------------- per-(block,head) attention ----------------
__global__ __launch_bounds__(256) void attn_kernel(const _Float16* __restrict__ qkvb,
                                                   const float* __restrict__ bias,
                                                   const float* __restrict__ mask,
                                                   _Float16* __restrict__ aout) {
    int bid = blockIdx.x;
    int n = bid >> 4, e = bid & 15;
    int t0 = n * KBLK;
    int valid = (T_DIM - t0 < KBLK) ? (T_DIM - t0) : KBLK;

    __shared__ _Float16 Qs[64 * 136];
    __shared__ _Float16 Ks[64 * 136];
    __shared__ _Float16 VTs[128 * 72];
    __shared__ _Float16 Ps[64 * 72];
    __shared__ float maskv[64];

    int tid = threadIdx.x;
    int lane = tid & 63, wave = tid >> 6;
    const _Float16* qp = qkvb + (size_t)e * (T_DIM * DH);
    const _Float16* kp = qkvb + (size_t)(T_DIM * H_DIM) + (size_t)e * (T_DIM * DH);
    const _Float16* vp = qkvb + (size_t)2 * (T_DIM * H_DIM) + (size_t)e * (T_DIM * DH);

#pragma unroll
    for (int i = 0; i < 4; i++) {
        int c = tid + i * 256;
        int r = c >> 4, c8 = c & 15;
        uint4 z = {0u, 0u, 0u, 0u};
        uint4 vq = z, vk = z;
        if (r < valid) {
            vq = *(const uint4*)&qp[(size_t)(t0 + r) * DH + c8 * 8];
            vk = *(const uint4*)&kp[(size_t)(t0 + r) * DH + c8 * 8];
        }
        *(uint4*)&Qs[r * 136 + c8 * 8] = vq;
        *(uint4*)&Ks[r * 136 + c8 * 8] = vk;
    }
#pragma unroll
    for (int i = 0; i < 4; i++) {
        int c = tid + i * 256;
        int r = c & 63;
        int f0 = (c >> 6) * 8;
        uint4 v = {0u, 0u, 0u, 0u};
        if (r < valid) v = *(const uint4*)&vp[(size_t)(t0 + r) * DH + f0];
        _Float16 tmp[8];
        *(uint4*)tmp = v;
#pragma unroll
        for (int j = 0; j < 8; j++) VTs[(f0 + j) * 72 + r] = tmp[j];
    }
    if (tid < 64) maskv[tid] = (tid < valid) ? mask[t0 + tid] : NEGV;
    __syncthreads();

    int qr0 = wave * 16;
    int cb = lane & 15, hi = lane >> 4;

    f16x8 aq[4];
#pragma unroll
    for (int ks = 0; ks < 4; ks++)
        aq[ks] = *(const f16x8*)&Qs[(qr0 + cb) * 136 + ks * 32 + hi * 8];
    f32x4 s[4];
#pragma unroll
    for (int kt = 0; kt < 4; kt++) s[kt] = (f32x4){0.f, 0.f, 0.f, 0.f};
#pragma unroll
    for (int kt = 0; kt < 4; kt++)
#pragma unroll
        for (int ks = 0; ks < 4; ks++) {
            f16x8 bk = *(const f16x8*)&Ks[(kt * 16 + cb) * 136 + ks * 32 + hi * 8];
            s[kt] = __builtin_amdgcn_mfma_f32_16x16x32_f16(aq[ks], bk, s[kt], 0, 0, 0);
        }

#pragma unroll
    for (int r = 0; r < 4; r++) {
        int rl = qr0 + hi * 4 + r;
        int qi = t0 + rl;
        float mq = maskv[rl];
        float lg[4];
        float mx = -3.4e38f;
#pragma unroll
        for (int kt = 0; kt < 4; kt++) {
            int cl = kt * 16 + cb, ki = t0 + cl;
            float bg = (qi < T_DIM && ki < T_DIM)
                           ? bias[((size_t)e * T_DIM + qi) * T_DIM + ki] : 0.f;
            float pr = mq * maskv[cl];
            float v = s[kt][r] + bg + (pr > 0.f ? 0.f : NEGV);
            lg[kt] = v;
            mx = fmaxf(mx, v);
        }
#pragma unroll
        for (int off = 8; off; off >>= 1) mx = fmaxf(mx, __shfl_xor(mx, off));
        float sum = 0.f;
#pragma unroll
        for (int kt = 0; kt < 4; kt++) {
            float pe = __expf(lg[kt] - mx);
            lg[kt] = pe;
            sum += pe;
        }
#pragma unroll
        for (int off = 8; off; off >>= 1) sum += __shfl_xor(sum, off);
        float inv = 1.f / sum;
#pragma unroll
        for (int kt = 0; kt < 4; kt++)
            Ps[rl * 72 + kt * 16 + cb] = (_Float16)(lg[kt] * inv);
    }
    __syncthreads();

    f16x8 pa[2];
#pragma unroll
    for (int ks = 0; ks < 2; ks++)
        pa[ks] = *(const f16x8*)&Ps[(qr0 + cb) * 72 + ks * 32 + hi * 8];
#pragma unroll
    for (int ft = 0; ft < 8; ft++) {
        f32x4 o = (f32x4){0.f, 0.f, 0.f, 0.f};
#pragma unroll
        for (int ks = 0; ks < 2; ks++) {
            f16x8 bv = *(const f16x8*)&VTs[(ft * 16 + cb) * 72 + ks * 32 + hi * 8];
            o = __builtin_amdgcn_mfma_f32_16x16x32_f16(pa[ks], bv, o, 0, 0, 0);
        }
#pragma unroll
        for (int r = 0; r < 4; r++) {
            int rl = qr0 + hi * 4 + r;
            if (rl < valid)
                aout[(size_t)(t0 + rl) * H_DIM + e * DH + ft * 16 + cb] = (_Float16)o[r];
        }
    }
}

extern "C" void kernel_launch(void* const* d_in, const int* in_sizes, int n_in,
                              void* d_out, int out_size, void* d_ws, size_t ws_size,
                              hipStream_t stream) {
    const float* x    = (const float*)d_in[0];
    const float* mask = (const float*)d_in[1];
    const float* bias = (const float*)d_in[2];
    const float* Wq   = (const float*)d_in[3];
    const float* Wk   = (const float*)d_in[4];
    const float* Wv   = (const float*)d_in[5];
    const float* Wo   = (const float*)d_in[6];
    float* out = (float*)d_out;

    _Float16* xb   = (_Float16*)d_ws;
    _Float16* WT   = xb + (size_t)T_DIM * H_DIM;
    _Float16* WoT  = WT + (size_t)3 * T_DIM * H_DIM;
    _Float16* qkvb = WoT + (size_t)T_DIM * H_DIM;
    _Float16* aout = qkvb + (size_t)3 * T_DIM * H_DIM;

    prep_kernel<<<dim3(64, 64, 5), dim3(32, 8), 0, stream>>>(x, Wq, Wk, Wv, Wo, xb, WT, WoT);

    // fused QKV projection: 256^2 8-phase kernel; grid 8x24 = 192 blocks
    gemm256_kernel<<<192, 512, 0, stream>>>(xb, WT, qkvb, H_DIM, 24);

    attn_kernel<<<NBLK * N_HEADS, 256, 0, stream>>>(qkvb, bias, mask, aout);

    gemm_kernel<1, 64><<<dim3(H_DIM / 64, T_DIM / 128), 256, 0, stream>>>(
        aout, WoT, (void*)out, T_DIM, H_DIM, H_DIM);
}

// Round 6
// 127.720 us; speedup vs baseline: 1.1187x; 1.1170x over previous
//
#include <hip/hip_runtime.h>
#include <hip/hip_bf16.h>

typedef _Float16 f16x8 __attribute__((ext_vector_type(8)));
typedef float f32x4 __attribute__((ext_vector_type(4)));

#define T_DIM 2048
#define H_DIM 2048
#define N_HEADS 16
#define DH 128
#define KBLK 50
#define NBLK 41
#define NEGV (-1.0e9f)
#define QSCALE 0.08838834764831845f  // 128^-0.5

__device__ __forceinline__ void gl_lds16(const void* g, void* l) {
    __builtin_amdgcn_global_load_lds(
        (const __attribute__((address_space(1))) void*)g,
        (__attribute__((address_space(3))) void*)l, 16, 0, 0);
}

// ---- fused prep: z<4 -> transpose weight fp32->fp16; z==4 -> convert x fp32->fp16 ----
__global__ __launch_bounds__(256) void prep_kernel(const float* __restrict__ x,
                                                   const float* __restrict__ Wq,
                                                   const float* __restrict__ Wk,
                                                   const float* __restrict__ Wv,
                                                   const float* __restrict__ Wo,
                                                   _Float16* __restrict__ xb,
                                                   _Float16* __restrict__ WT,
                                                   _Float16* __restrict__ WoT) {
    __shared__ float tile[32][33];
    int z = blockIdx.z;
    const float* src = (z == 0) ? Wq : (z == 1) ? Wk : (z == 2) ? Wv : (z == 3) ? Wo : x;
    _Float16* dst = (z == 3) ? WoT : (z == 4) ? xb : (WT + (size_t)z * T_DIM * H_DIM);
    int bx = blockIdx.x * 32, by = blockIdx.y * 32;
    int tx = threadIdx.x, ty = threadIdx.y;  // 32 x 8
    if (z == 4) {
#pragma unroll
        for (int i = 0; i < 4; i++) {
            int r = by + ty + i * 8;
            dst[(size_t)r * H_DIM + bx + tx] = (_Float16)src[(size_t)r * H_DIM + bx + tx];
        }
    } else {
#pragma unroll
        for (int i = 0; i < 4; i++)
            tile[ty + i * 8][tx] = src[(size_t)(by + ty + i * 8) * H_DIM + bx + tx];
        __syncthreads();
#pragma unroll
        for (int i = 0; i < 4; i++)
            dst[(size_t)(bx + ty + i * 8) * H_DIM + by + tx] = (_Float16)tile[tx][ty + i * 8];
    }
}

// =============== QKV projection: 256x192 tile, 4-phase, grid 256 (1 block/CU) ============
// BM=256, BN=192, BK=64, 512 threads = 8 waves (2M x 4N), per-wave C = 128x48 (8x3 frags).
// LDS: A 2x32KB + B 2x24KB = 112KB, double-buffered, T2 XOR-swizzle (linear gl_lds dest +
// pre-swizzled source + swizzled ds_read). Stage units: A0..A3, B0..B2 (8KB each = 1 gl_lds
// per thread). Schedule per iter t: ph0 stages B0,B1(t+1); ph1 stages B2(t+1); ph2 stages
// A0,A1(t+2); ph3 stages A2,A3(t+2). All ds_reads in ph0/ph1 (drained by lgkmcnt(0) before
// their MFMA, hence before ph1-end barrier => buffer writable from ph2 on).
// vmcnt at (t,ph3): outstanding = 7 units of t+1 + 4 A-units of t+2 => vmcnt(4) confirms
// tile t+1 block-wide after barrier. Tail: vmcnt(0) at t=NT-2.
__global__ __launch_bounds__(512, 2) void qkv192_kernel(const _Float16* __restrict__ A,
                                                        const _Float16* __restrict__ BT,
                                                        _Float16* __restrict__ qkv) {
    const int K = 2048, NT = 32;
    __shared__ _Float16 sA[2][16384];  // 256 rows x 64
    __shared__ _Float16 sB[2][12288];  // 192 rows x 64

    int tid = threadIdx.x;
    int lane = tid & 63, wave = tid >> 6;
    int wm = wave >> 2, wn = wave & 3;
    int cb = lane & 15, hi = lane >> 4;

    // XCD swizzle: 256 = 8 XCDs x 32; each XCD owns one full M-row (A panel L2-resident)
    int bid = blockIdx.x;
    int swz = (bid & 7) * 32 + (bid >> 3);
    int by = swz >> 5, bx = swz & 31;
    int bm = by * 256, bn = bx * 192;

    f32x4 acc[8][3];
#pragma unroll
    for (int m = 0; m < 8; m++)
#pragma unroll
        for (int n = 0; n < 3; n++) acc[m][n] = (f32x4){0.f, 0.f, 0.f, 0.f};

    int rp = tid >> 3, cc = tid & 7;
    int scol = ((cc ^ (rp & 7)) << 3);  // pre-swizzled source col (f16 units)

    auto stageA = [&](int t, int u) {
        int buf = t & 1;
        gl_lds16(A + (size_t)(bm + u * 64 + rp) * K + (t << 6) + scol,
                 (buf ? sA[1] : sA[0]) + u * 4096 + tid * 8);
    };
    auto stageB = [&](int t, int u) {
        int buf = t & 1;
        gl_lds16(BT + (size_t)(bn + u * 64 + rp) * K + (t << 6) + scol,
                 (buf ? sB[1] : sB[0]) + u * 4096 + tid * 8);
    };

    f16x8 a_lo[4][2], a_hi[4][2], b01[2][2], b2[2];

    // prologue: tile0 all 7 units + tile1 A units; confirm tile0 (4 in flight)
    stageA(0, 0); stageA(0, 1); stageA(0, 2); stageA(0, 3);
    stageB(0, 0); stageB(0, 1); stageB(0, 2);
    stageA(1, 0); stageA(1, 1); stageA(1, 2); stageA(1, 3);
    asm volatile("s_waitcnt vmcnt(4)" ::: "memory");
    __builtin_amdgcn_s_barrier();

    for (int t = 0; t < NT; t++) {
        int buf = t & 1;
        const char* bA = (const char*)(buf ? sA[1] : sA[0]);
        const char* bB = (const char*)(buf ? sB[1] : sB[0]);
        // ---- ph0: read a_lo + b01; stage B0,B1(t+1); MFMA a_lo x b01 (16) ----
#pragma unroll
        for (int mf = 0; mf < 4; mf++) {
            int ra = wm * 128 + mf * 16 + cb;
#pragma unroll
            for (int ks = 0; ks < 2; ks++)
                a_lo[mf][ks] = *(const f16x8*)(bA + (ra << 7) +
                                               ((ks * 64 + hi * 16) ^ ((ra & 7) << 4)));
        }
#pragma unroll
        for (int nf = 0; nf < 2; nf++) {
            int rb = wn * 48 + nf * 16 + cb;
#pragma unroll
            for (int ks = 0; ks < 2; ks++)
                b01[nf][ks] = *(const f16x8*)(bB + (rb << 7) +
                                              ((ks * 64 + hi * 16) ^ ((rb & 7) << 4)));
        }
        if (t + 1 < NT) { stageB(t + 1, 0); stageB(t + 1, 1); }
        __builtin_amdgcn_s_barrier();
        asm volatile("s_waitcnt lgkmcnt(0)" ::: "memory");
        __builtin_amdgcn_s_setprio(1);
#pragma unroll
        for (int mf = 0; mf < 4; mf++)
#pragma unroll
            for (int nf = 0; nf < 2; nf++)
#pragma unroll
                for (int ks = 0; ks < 2; ks++)
                    acc[mf][nf] = __builtin_amdgcn_mfma_f32_16x16x32_f16(a_lo[mf][ks], b01[nf][ks], acc[mf][nf], 0, 0, 0);
        __builtin_amdgcn_s_setprio(0);
        __builtin_amdgcn_s_barrier();

        // ---- ph1: read a_hi + b2; stage B2(t+1); MFMA a_hi x b2 (8) ----
#pragma unroll
        for (int mf = 0; mf < 4; mf++) {
            int ra = wm * 128 + 64 + mf * 16 + cb;
#pragma unroll
            for (int ks = 0; ks < 2; ks++)
                a_hi[mf][ks] = *(const f16x8*)(bA + (ra << 7) +
                                               ((ks * 64 + hi * 16) ^ ((ra & 7) << 4)));
        }
        {
            int rb = wn * 48 + 32 + cb;
#pragma unroll
            for (int ks = 0; ks < 2; ks++)
                b2[ks] = *(const f16x8*)(bB + (rb << 7) +
                                         ((ks * 64 + hi * 16) ^ ((rb & 7) << 4)));
        }
        if (t + 1 < NT) stageB(t + 1, 2);
        __builtin_amdgcn_s_barrier();
        asm volatile("s_waitcnt lgkmcnt(0)" ::: "memory");
        __builtin_amdgcn_s_setprio(1);
#pragma unroll
        for (int mf = 0; mf < 4; mf++)
#pragma unroll
            for (int ks = 0; ks < 2; ks++)
                acc[4 + mf][2] = __builtin_amdgcn_mfma_f32_16x16x32_f16(a_hi[mf][ks], b2[ks], acc[4 + mf][2], 0, 0, 0);
        __builtin_amdgcn_s_setprio(0);
        __builtin_amdgcn_s_barrier();

        // ---- ph2: stage A0,A1(t+2); MFMA a_lo x b2 (8) ----
        if (t + 2 < NT) { stageA(t + 2, 0); stageA(t + 2, 1); }
        __builtin_amdgcn_s_barrier();
        __builtin_amdgcn_s_setprio(1);
#pragma unroll
        for (int mf = 0; mf < 4; mf++)
#pragma unroll
            for (int ks = 0; ks < 2; ks++)
                acc[mf][2] = __builtin_amdgcn_mfma_f32_16x16x32_f16(a_lo[mf][ks], b2[ks], acc[mf][2], 0, 0, 0);
        __builtin_amdgcn_s_setprio(0);
        __builtin_amdgcn_s_barrier();

        // ---- ph3: stage A2,A3(t+2); vmcnt confirms tile t+1; MFMA a_hi x b01 (16) ----
        if (t + 2 < NT) { stageA(t + 2, 2); stageA(t + 2, 3); }
        if (t < NT - 2)
            asm volatile("s_waitcnt vmcnt(4)" ::: "memory");
        else if (t == NT - 2)
            asm volatile("s_waitcnt vmcnt(0)" ::: "memory");
        __builtin_amdgcn_s_barrier();
        __builtin_amdgcn_s_setprio(1);
#pragma unroll
        for (int mf = 0; mf < 4; mf++)
#pragma unroll
            for (int nf = 0; nf < 2; nf++)
#pragma unroll
                for (int ks = 0; ks < 2; ks++)
                    acc[4 + mf][nf] = __builtin_amdgcn_mfma_f32_16x16x32_f16(a_hi[mf][ks], b01[nf][ks], acc[4 + mf][nf], 0, 0, 0);
        __builtin_amdgcn_s_setprio(0);
        __builtin_amdgcn_s_barrier();
    }

    // epilogue: scatter to q/k/v fp16 [tensor][e][t][f], scale q by QSCALE
#pragma unroll
    for (int mf = 0; mf < 8; mf++) {
#pragma unroll
        for (int nf = 0; nf < 3; nf++) {
            int gn = bn + wn * 48 + nf * 16 + cb;
            int tensor = gn >> 11;
            int ef = gn & 2047;
            int e = ef >> 7, f = ef & 127;
            float scale = (tensor == 0) ? QSCALE : 1.0f;
            _Float16* base = qkv + (size_t)tensor * (T_DIM * H_DIM) + (size_t)e * (T_DIM * DH) + f;
#pragma unroll
            for (int r = 0; r < 4; r++) {
                int gm = bm + wm * 128 + mf * 16 + hi * 4 + r;
                base[(size_t)gm * DH] = (_Float16)(acc[mf][nf][r] * scale);
            }
        }
    }
}

// =============== out-proj: 256x256 8-phase, split-K=4, fp16 partials =================
// grid 256 = 64 tiles x 4 splits; each block K-range 512 (NT=8). Same ledger as round-5
// gemm256 (proven): vmcnt(4) per K-tile at ph3, tail vmcnt(0) at NT-2.
__global__ __launch_bounds__(512, 2) void oproj_kernel(const _Float16* __restrict__ A,
                                                       const _Float16* __restrict__ BT,
                                                       _Float16* __restrict__ part) {
    const int K = 2048, NT = 8;
    __shared__ _Float16 sA[2][16384];
    __shared__ _Float16 sB[2][16384];

    int tid = threadIdx.x;
    int lane = tid & 63, wave = tid >> 6;
    int wm = wave >> 2, wn = wave & 3;
    int cb = lane & 15, hi = lane >> 4;

    int bid = blockIdx.x;
    int s = bid & 3, tile = bid >> 2;
    int by = tile >> 3, bx = tile & 7;
    int bm = by * 256, bn = bx * 256;
    int kbase = s * 512;

    f32x4 acc[8][4];
#pragma unroll
    for (int m = 0; m < 8; m++)
#pragma unroll
        for (int n = 0; n < 4; n++) acc[m][n] = (f32x4){0.f, 0.f, 0.f, 0.f};

    auto stageP = [&](int t, int p) {
        int buf = t & 1, k0 = kbase + (t << 6);
        const _Float16* src = (p < 2) ? A + (size_t)(bm + ((p & 1) << 7)) * K + k0
                                      : BT + (size_t)(bn + ((p & 1) << 7)) * K + k0;
        _Float16* dst = ((p < 2) ? (buf ? sA[1] : sA[0]) : (buf ? sB[1] : sB[0])) + ((p & 1) << 13);
#pragma unroll
        for (int l = 0; l < 2; l++) {
            int c = l * 512 + tid;
            int rp = c >> 3, cc = c & 7;
            int col = (cc ^ (rp & 7)) << 3;
            gl_lds16(src + (size_t)rp * K + col, dst + c * 8);
        }
    };

    f16x8 a_lo[4][2], a_hi[4][2], b_lo[2][2], b_hi[2][2];

    stageP(0, 0); stageP(0, 1); stageP(0, 2); stageP(0, 3);
    stageP(1, 0); stageP(1, 1);
    asm volatile("s_waitcnt vmcnt(4)" ::: "memory");
    __builtin_amdgcn_s_barrier();

    for (int t = 0; t < NT; t++) {
        int buf = t & 1;
        const char* bA = (const char*)(buf ? sA[1] : sA[0]);
        const char* bB = (const char*)(buf ? sB[1] : sB[0]);
        // ph0
#pragma unroll
        for (int m = 0; m < 4; m++) {
            int ra = wm * 128 + m * 16 + cb;
#pragma unroll
            for (int ks = 0; ks < 2; ks++)
                a_lo[m][ks] = *(const f16x8*)(bA + (ra << 7) +
                                              ((ks * 64 + hi * 16) ^ ((ra & 7) << 4)));
        }
#pragma unroll
        for (int n = 0; n < 2; n++) {
            int rb = wn * 64 + n * 16 + cb;
#pragma unroll
            for (int ks = 0; ks < 2; ks++)
                b_lo[n][ks] = *(const f16x8*)(bB + (rb << 7) +
                                              ((ks * 64 + hi * 16) ^ ((rb & 7) << 4)));
        }
        if (t + 1 < NT) stageP(t + 1, 2);
        __builtin_amdgcn_s_barrier();
        asm volatile("s_waitcnt lgkmcnt(0)" ::: "memory");
        __builtin_amdgcn_s_setprio(1);
#pragma unroll
        for (int m = 0; m < 4; m++)
#pragma unroll
            for (int n = 0; n < 2; n++)
#pragma unroll
                for (int ks = 0; ks < 2; ks++)
                    acc[m][n] = __builtin_amdgcn_mfma_f32_16x16x32_f16(a_lo[m][ks], b_lo[n][ks], acc[m][n], 0, 0, 0);
        __builtin_amdgcn_s_setprio(0);
        __builtin_amdgcn_s_barrier();

        // ph1
#pragma unroll
        for (int m = 0; m < 4; m++) {
            int ra = wm * 128 + 64 + m * 16 + cb;
#pragma unroll
            for (int ks = 0; ks < 2; ks++)
                a_hi[m][ks] = *(const f16x8*)(bA + (ra << 7) +
                                              ((ks * 64 + hi * 16) ^ ((ra & 7) << 4)));
        }
#pragma unroll
        for (int n = 0; n < 2; n++) {
            int rb = wn * 64 + 32 + n * 16 + cb;
#pragma unroll
            for (int ks = 0; ks < 2; ks++)
                b_hi[n][ks] = *(const f16x8*)(bB + (rb << 7) +
                                              ((ks * 64 + hi * 16) ^ ((rb & 7) << 4)));
        }
        if (t + 1 < NT) stageP(t + 1, 3);
        __builtin_amdgcn_s_barrier();
        asm volatile("s_waitcnt lgkmcnt(0)" ::: "memory");
        __builtin_amdgcn_s_setprio(1);
#pragma unroll
        for (int m = 0; m < 4; m++)
#pragma unroll
            for (int n = 0; n < 2; n++)
#pragma unroll
                for (int ks = 0; ks < 2; ks++)
                    acc[4 + m][2 + n] = __builtin_amdgcn_mfma_f32_16x16x32_f16(a_hi[m][ks], b_hi[n][ks], acc[4 + m][2 + n], 0, 0, 0);
        __builtin_amdgcn_s_setprio(0);
        __builtin_amdgcn_s_barrier();

        // ph2
        if (t + 2 < NT) stageP(t + 2, 0);
        __builtin_amdgcn_s_barrier();
        __builtin_amdgcn_s_setprio(1);
#pragma unroll
        for (int m = 0; m < 4; m++)
#pragma unroll
            for (int n = 0; n < 2; n++)
#pragma unroll
                for (int ks = 0; ks < 2; ks++)
                    acc[m][2 + n] = __builtin_amdgcn_mfma_f32_16x16x32_f16(a_lo[m][ks], b_hi[n][ks], acc[m][2 + n], 0, 0, 0);
        __builtin_amdgcn_s_setprio(0);
        __builtin_amdgcn_s_barrier();

        // ph3
        if (t + 2 < NT) stageP(t + 2, 1);
        if (t < NT - 2)
            asm volatile("s_waitcnt vmcnt(4)" ::: "memory");
        else if (t == NT - 2)
            asm volatile("s_waitcnt vmcnt(0)" ::: "memory");
        __builtin_amdgcn_s_barrier();
        __builtin_amdgcn_s_setprio(1);
#pragma unroll
        for (int m = 0; m < 4; m++)
#pragma unroll
            for (int n = 0; n < 2; n++)
#pragma unroll
                for (int ks = 0; ks < 2; ks++)
                    acc[4 + m][n] = __builtin_amdgcn_mfma_f32_16x16x32_f16(a_hi[m][ks], b_lo[n][ks], acc[4 + m][n], 0, 0, 0);
        __builtin_amdgcn_s_setprio(0);
        __builtin_amdgcn_s_barrier();
    }

    _Float16* pb = part + (size_t)s * T_DIM * H_DIM;
#pragma unroll
    for (int m = 0; m < 8; m++)
#pragma unroll
        for (int n = 0; n < 4; n++) {
            int gn = bn + wn * 64 + ((n & 1) * 16) + ((n >> 1) * 32) + cb;
#pragma unroll
            for (int r = 0; r < 4; r++) {
                int gm = bm + wm * 128 + ((m & 3) * 16) + ((m >> 2) * 64) + hi * 4 + r;
                pb[(size_t)gm * H_DIM + gn] = (_Float16)acc[m][n][r];
            }
        }
}

// ---------------- reduce 4 fp16 partials -> fp32 out ----------------
__global__ __launch_bounds__(256) void reduce4_kernel(const _Float16* __restrict__ part,
                                                      float* __restrict__ out) {
    const size_t S = (size_t)T_DIM * H_DIM;
    int i = (blockIdx.x * 256 + threadIdx.x) * 8;
    f16x8 p0 = *(const f16x8*)&part[i];
    f16x8 p1 = *(const f16x8*)&part[S + i];
    f16x8 p2 = *(const f16x8*)&part[2 * S + i];
    f16x8 p3 = *(const f16x8*)&part[3 * S + i];
#pragma unroll
    for (int j = 0; j < 8; j++)
        out[i + j] = (float)p0[j] + (float)p1[j] + (float)p2[j] + (float)p3[j];
}

// ---------------- per-(block,head) attention ----------------
__global__ __launch_bounds__(256) void attn_kernel(const _Float16* __restrict__ qkvb,
                                                   const float* __restrict__ bias,
                                                   const float* __restrict__ mask,
                                                   _Float16* __restrict__ aout) {
    int bid = blockIdx.x;
    int n = bid >> 4, e = bid & 15;
    int t0 = n * KBLK;
    int valid = (T_DIM - t0 < KBLK) ? (T_DIM - t0) : KBLK;

    __shared__ _Float16 Qs[64 * 136];
    __shared__ _Float16 Ks[64 * 136];
    __shared__ _Float16 VTs[128 * 72];
    __shared__ _Float16 Ps[64 * 72];
    __shared__ float maskv[64];

    int tid = threadIdx.x;
    int lane = tid & 63, wave = tid >> 6;
    const _Float16* qp = qkvb + (size_t)e * (T_DIM * DH);
    const _Float16* kp = qkvb + (size_t)(T_DIM * H_DIM) + (size_t)e * (T_DIM * DH);
    const _Float16* vp = qkvb + (size_t)2 * (T_DIM * H_DIM) + (size_t)e * (T_DIM * DH);

#pragma unroll
    for (int i = 0; i < 4; i++) {
        int c = tid + i * 256;
        int r = c >> 4, c8 = c & 15;
        uint4 z = {0u, 0u, 0u, 0u};
        uint4 vq = z, vk = z;
        if (r < valid) {
            vq = *(const uint4*)&qp[(size_t)(t0 + r) * DH + c8 * 8];
            vk = *(const uint4*)&kp[(size_t)(t0 + r) * DH + c8 * 8];
        }
        *(uint4*)&Qs[r * 136 + c8 * 8] = vq;
        *(uint4*)&Ks[r * 136 + c8 * 8] = vk;
    }
#pragma unroll
    for (int i = 0; i < 4; i++) {
        int c = tid + i * 256;
        int r = c & 63;
        int f0 = (c >> 6) * 8;
        uint4 v = {0u, 0u, 0u, 0u};
        if (r < valid) v = *(const uint4*)&vp[(size_t)(t0 + r) * DH + f0];
        _Float16 tmp[8];
        *(uint4*)tmp = v;
#pragma unroll
        for (int j = 0; j < 8; j++) VTs[(f0 + j) * 72 + r] = tmp[j];
    }
    if (tid < 64) maskv[tid] = (tid < valid) ? mask[t0 + tid] : NEGV;
    __syncthreads();

    int qr0 = wave * 16;
    int cb = lane & 15, hi = lane >> 4;

    f16x8 aq[4];
#pragma unroll
    for (int ks = 0; ks < 4; ks++)
        aq[ks] = *(const f16x8*)&Qs[(qr0 + cb) * 136 + ks * 32 + hi * 8];
    f32x4 s[4];
#pragma unroll
    for (int kt = 0; kt < 4; kt++) s[kt] = (f32x4){0.f, 0.f, 0.f, 0.f};
#pragma unroll
    for (int kt = 0; kt < 4; kt++)
#pragma unroll
        for (int ks = 0; ks < 4; ks++) {
            f16x8 bk = *(const f16x8*)&Ks[(kt * 16 + cb) * 136 + ks * 32 + hi * 8];
            s[kt] = __builtin_amdgcn_mfma_f32_16x16x32_f16(aq[ks], bk, s[kt], 0, 0, 0);
        }

#pragma unroll
    for (int r = 0; r < 4; r++) {
        int rl = qr0 + hi * 4 + r;
        int qi = t0 + rl;
        float mq = maskv[rl];
        float lg[4];
        float mx = -3.4e38f;
#pragma unroll
        for (int kt = 0; kt < 4; kt++) {
            int cl = kt * 16 + cb, ki = t0 + cl;
            float bg = (qi < T_DIM && ki < T_DIM)
                           ? bias[((size_t)e * T_DIM + qi) * T_DIM + ki] : 0.f;
            float pr = mq * maskv[cl];
            float v = s[kt][r] + bg + (pr > 0.f ? 0.f : NEGV);
            lg[kt] = v;
            mx = fmaxf(mx, v);
        }
#pragma unroll
        for (int off = 8; off; off >>= 1) mx = fmaxf(mx, __shfl_xor(mx, off));
        float sum = 0.f;
#pragma unroll
        for (int kt = 0; kt < 4; kt++) {
            float pe = __expf(lg[kt] - mx);
            lg[kt] = pe;
            sum += pe;
        }
#pragma unroll
        for (int off = 8; off; off >>= 1) sum += __shfl_xor(sum, off);
        float inv = 1.f / sum;
#pragma unroll
        for (int kt = 0; kt < 4; kt++)
            Ps[rl * 72 + kt * 16 + cb] = (_Float16)(lg[kt] * inv);
    }
    __syncthreads();

    f16x8 pa[2];
#pragma unroll
    for (int ks = 0; ks < 2; ks++)
        pa[ks] = *(const f16x8*)&Ps[(qr0 + cb) * 72 + ks * 32 + hi * 8];
#pragma unroll
    for (int ft = 0; ft < 8; ft++) {
        f32x4 o = (f32x4){0.f, 0.f, 0.f, 0.f};
#pragma unroll
        for (int ks = 0; ks < 2; ks++) {
            f16x8 bv = *(const f16x8*)&VTs[(ft * 16 + cb) * 72 + ks * 32 + hi * 8];
            o = __builtin_amdgcn_mfma_f32_16x16x32_f16(pa[ks], bv, o, 0, 0, 0);
        }
#pragma unroll
        for (int r = 0; r < 4; r++) {
            int rl = qr0 + hi * 4 + r;
            if (rl < valid)
                aout[(size_t)(t0 + rl) * H_DIM + e * DH + ft * 16 + cb] = (_Float16)o[r];
        }
    }
}

extern "C" void kernel_launch(void* const* d_in, const int* in_sizes, int n_in,
                              void* d_out, int out_size, void* d_ws, size_t ws_size,
                              hipStream_t stream) {
    const float* x    = (const float*)d_in[0];
    const float* mask = (const float*)d_in[1];
    const float* bias = (const float*)d_in[2];
    const float* Wq   = (const float*)d_in[3];
    const float* Wk   = (const float*)d_in[4];
    const float* Wv   = (const float*)d_in[5];
    const float* Wo   = (const float*)d_in[6];
    float* out = (float*)d_out;

    // ws layout (f16): xb[4M] | WT[12M] | WoT[4M] | qkv[12M] | aout[4M] | part[16M] = 104MB
    _Float16* xb   = (_Float16*)d_ws;
    _Float16* WT   = xb + (size_t)T_DIM * H_DIM;
    _Float16* WoT  = WT + (size_t)3 * T_DIM * H_DIM;
    _Float16* qkvb = WoT + (size_t)T_DIM * H_DIM;
    _Float16* aout = qkvb + (size_t)3 * T_DIM * H_DIM;
    _Float16* part = aout + (size_t)T_DIM * H_DIM;

    prep_kernel<<<dim3(64, 64, 5), dim3(32, 8), 0, stream>>>(x, Wq, Wk, Wv, Wo, xb, WT, WoT);

    // QKV projection: 256x192 tiles -> 256 blocks (1/CU, no idle CUs)
    qkv192_kernel<<<256, 512, 0, stream>>>(xb, WT, qkvb);

    attn_kernel<<<NBLK * N_HEADS, 256, 0, stream>>>(qkvb, bias, mask, aout);

    // out-proj: split-K=4 -> 256 blocks, fp16 partials, then reduce
    oproj_kernel<<<256, 512, 0, stream>>>(aout, WoT, part);
    reduce4_kernel<<<(T_DIM * H_DIM) / (256 * 8), 256, 0, stream>>>(part, out);
}

// Round 7
// 126.987 us; speedup vs baseline: 1.1251x; 1.0058x over previous
//
#include <hip/hip_runtime.h>
#include <hip/hip_bf16.h>

typedef _Float16 f16x8 __attribute__((ext_vector_type(8)));
typedef float f32x4 __attribute__((ext_vector_type(4)));

#define T_DIM 2048
#define H_DIM 2048
#define N_HEADS 16
#define DH 128
#define KBLK 50
#define NBLK 41
#define NEGV (-1.0e9f)
#define QSCALE 0.08838834764831845f  // 128^-0.5

__device__ __forceinline__ void gl_lds16(const void* g, void* l) {
    __builtin_amdgcn_global_load_lds(
        (const __attribute__((address_space(1))) void*)g,
        (__attribute__((address_space(3))) void*)l, 16, 0, 0);
}

// ---- fused prep: z<4 -> transpose weight fp32->fp16; z==4 -> convert x fp32->fp16 ----
__global__ __launch_bounds__(256) void prep_kernel(const float* __restrict__ x,
                                                   const float* __restrict__ Wq,
                                                   const float* __restrict__ Wk,
                                                   const float* __restrict__ Wv,
                                                   const float* __restrict__ Wo,
                                                   _Float16* __restrict__ xb,
                                                   _Float16* __restrict__ WT,
                                                   _Float16* __restrict__ WoT) {
    __shared__ float tile[32][33];
    int z = blockIdx.z;
    int tx = threadIdx.x, ty = threadIdx.y;  // 32 x 8
    if (z == 4) {
        // vectorized convert: 2048 blocks needed; by>=32 idle
        if (blockIdx.y >= 32) return;
        int flat = blockIdx.y * 64 + blockIdx.x;
        int i = (flat * 256 + ty * 32 + tx) * 8;
        float4 a = *(const float4*)&x[i];
        float4 b = *(const float4*)&x[i + 4];
        f16x8 o = {(_Float16)a.x, (_Float16)a.y, (_Float16)a.z, (_Float16)a.w,
                   (_Float16)b.x, (_Float16)b.y, (_Float16)b.z, (_Float16)b.w};
        *(f16x8*)&xb[i] = o;
        return;
    }
    const float* src = (z == 0) ? Wq : (z == 1) ? Wk : (z == 2) ? Wv : Wo;
    _Float16* dst = (z == 3) ? WoT : (WT + (size_t)z * T_DIM * H_DIM);
    int bx = blockIdx.x * 32, by = blockIdx.y * 32;
#pragma unroll
    for (int i = 0; i < 4; i++)
        tile[ty + i * 8][tx] = src[(size_t)(by + ty + i * 8) * H_DIM + bx + tx];
    __syncthreads();
#pragma unroll
    for (int i = 0; i < 4; i++)
        dst[(size_t)(bx + ty + i * 8) * H_DIM + by + tx] = (_Float16)tile[tx][ty + i * 8];
}

// =============== QKV projection: 256x192 tile, 4-phase, grid 256 (1 block/CU) ============
// Same proven ledger as round 6. NEW: epilogue repacks C through LDS (two 128-row passes,
// [128][200] padded layout) -> coalesced uint4 global stores instead of 2B scatter.
__global__ __launch_bounds__(512, 2) void qkv192_kernel(const _Float16* __restrict__ A,
                                                        const _Float16* __restrict__ BT,
                                                        _Float16* __restrict__ qkv) {
    const int K = 2048, NT = 32;
    __shared__ _Float16 smem[57344];  // 112KB: A dbuf 2x16384 | B dbuf 2x12288
    _Float16* sA0 = smem;
    _Float16* sA1 = smem + 16384;
    _Float16* sB0 = smem + 32768;
    _Float16* sB1 = smem + 45056;

    int tid = threadIdx.x;
    int lane = tid & 63, wave = tid >> 6;
    int wm = wave >> 2, wn = wave & 3;
    int cb = lane & 15, hi = lane >> 4;

    int bid = blockIdx.x;
    int swz = (bid & 7) * 32 + (bid >> 3);
    int by = swz >> 5, bx = swz & 31;
    int bm = by * 256, bn = bx * 192;

    f32x4 acc[8][3];
#pragma unroll
    for (int m = 0; m < 8; m++)
#pragma unroll
        for (int n = 0; n < 3; n++) acc[m][n] = (f32x4){0.f, 0.f, 0.f, 0.f};

    int rp = tid >> 3, cc = tid & 7;
    int scol = ((cc ^ (rp & 7)) << 3);  // pre-swizzled source col (f16 units)

    auto stageA = [&](int t, int u) {
        int buf = t & 1;
        gl_lds16(A + (size_t)(bm + u * 64 + rp) * K + (t << 6) + scol,
                 (buf ? sA1 : sA0) + u * 4096 + tid * 8);
    };
    auto stageB = [&](int t, int u) {
        int buf = t & 1;
        gl_lds16(BT + (size_t)(bn + u * 64 + rp) * K + (t << 6) + scol,
                 (buf ? sB1 : sB0) + u * 4096 + tid * 8);
    };

    f16x8 a_lo[4][2], a_hi[4][2], b01[2][2], b2[2];

    stageA(0, 0); stageA(0, 1); stageA(0, 2); stageA(0, 3);
    stageB(0, 0); stageB(0, 1); stageB(0, 2);
    stageA(1, 0); stageA(1, 1); stageA(1, 2); stageA(1, 3);
    asm volatile("s_waitcnt vmcnt(4)" ::: "memory");
    __builtin_amdgcn_s_barrier();

    for (int t = 0; t < NT; t++) {
        int buf = t & 1;
        const char* bA = (const char*)(buf ? sA1 : sA0);
        const char* bB = (const char*)(buf ? sB1 : sB0);
        // ph0: read a_lo + b01; stage B0,B1(t+1); MFMA a_lo x b01
#pragma unroll
        for (int mf = 0; mf < 4; mf++) {
            int ra = wm * 128 + mf * 16 + cb;
#pragma unroll
            for (int ks = 0; ks < 2; ks++)
                a_lo[mf][ks] = *(const f16x8*)(bA + (ra << 7) +
                                               ((ks * 64 + hi * 16) ^ ((ra & 7) << 4)));
        }
#pragma unroll
        for (int nf = 0; nf < 2; nf++) {
            int rb = wn * 48 + nf * 16 + cb;
#pragma unroll
            for (int ks = 0; ks < 2; ks++)
                b01[nf][ks] = *(const f16x8*)(bB + (rb << 7) +
                                              ((ks * 64 + hi * 16) ^ ((rb & 7) << 4)));
        }
        if (t + 1 < NT) { stageB(t + 1, 0); stageB(t + 1, 1); }
        __builtin_amdgcn_s_barrier();
        asm volatile("s_waitcnt lgkmcnt(0)" ::: "memory");
        __builtin_amdgcn_s_setprio(1);
#pragma unroll
        for (int mf = 0; mf < 4; mf++)
#pragma unroll
            for (int nf = 0; nf < 2; nf++)
#pragma unroll
                for (int ks = 0; ks < 2; ks++)
                    acc[mf][nf] = __builtin_amdgcn_mfma_f32_16x16x32_f16(a_lo[mf][ks], b01[nf][ks], acc[mf][nf], 0, 0, 0);
        __builtin_amdgcn_s_setprio(0);
        __builtin_amdgcn_s_barrier();

        // ph1: read a_hi + b2; stage B2(t+1); MFMA a_hi x b2
#pragma unroll
        for (int mf = 0; mf < 4; mf++) {
            int ra = wm * 128 + 64 + mf * 16 + cb;
#pragma unroll
            for (int ks = 0; ks < 2; ks++)
                a_hi[mf][ks] = *(const f16x8*)(bA + (ra << 7) +
                                               ((ks * 64 + hi * 16) ^ ((ra & 7) << 4)));
        }
        {
            int rb = wn * 48 + 32 + cb;
#pragma unroll
            for (int ks = 0; ks < 2; ks++)
                b2[ks] = *(const f16x8*)(bB + (rb << 7) +
                                         ((ks * 64 + hi * 16) ^ ((rb & 7) << 4)));
        }
        if (t + 1 < NT) stageB(t + 1, 2);
        __builtin_amdgcn_s_barrier();
        asm volatile("s_waitcnt lgkmcnt(0)" ::: "memory");
        __builtin_amdgcn_s_setprio(1);
#pragma unroll
        for (int mf = 0; mf < 4; mf++)
#pragma unroll
            for (int ks = 0; ks < 2; ks++)
                acc[4 + mf][2] = __builtin_amdgcn_mfma_f32_16x16x32_f16(a_hi[mf][ks], b2[ks], acc[4 + mf][2], 0, 0, 0);
        __builtin_amdgcn_s_setprio(0);
        __builtin_amdgcn_s_barrier();

        // ph2: stage A0,A1(t+2); MFMA a_lo x b2
        if (t + 2 < NT) { stageA(t + 2, 0); stageA(t + 2, 1); }
        __builtin_amdgcn_s_barrier();
        __builtin_amdgcn_s_setprio(1);
#pragma unroll
        for (int mf = 0; mf < 4; mf++)
#pragma unroll
            for (int ks = 0; ks < 2; ks++)
                acc[mf][2] = __builtin_amdgcn_mfma_f32_16x16x32_f16(a_lo[mf][ks], b2[ks], acc[mf][2], 0, 0, 0);
        __builtin_amdgcn_s_setprio(0);
        __builtin_amdgcn_s_barrier();

        // ph3: stage A2,A3(t+2); vmcnt confirms tile t+1; MFMA a_hi x b01
        if (t + 2 < NT) { stageA(t + 2, 2); stageA(t + 2, 3); }
        if (t < NT - 2)
            asm volatile("s_waitcnt vmcnt(4)" ::: "memory");
        else if (t == NT - 2)
            asm volatile("s_waitcnt vmcnt(0)" ::: "memory");
        __builtin_amdgcn_s_barrier();
        __builtin_amdgcn_s_setprio(1);
#pragma unroll
        for (int mf = 0; mf < 4; mf++)
#pragma unroll
            for (int nf = 0; nf < 2; nf++)
#pragma unroll
                for (int ks = 0; ks < 2; ks++)
                    acc[4 + mf][nf] = __builtin_amdgcn_mfma_f32_16x16x32_f16(a_hi[mf][ks], b01[nf][ks], acc[4 + mf][nf], 0, 0, 0);
        __builtin_amdgcn_s_setprio(0);
        __builtin_amdgcn_s_barrier();
    }

    // ---- epilogue: LDS repack (two 128-row passes, [128][200]) -> uint4 stores ----
#pragma unroll
    for (int p = 0; p < 2; p++) {
        if (p) __builtin_amdgcn_s_barrier();
        if (wm == p) {
#pragma unroll
            for (int mf = 0; mf < 8; mf++)
#pragma unroll
                for (int nf = 0; nf < 3; nf++) {
                    int col = wn * 48 + nf * 16 + cb;
                    float sc = ((bn + col) >> 11) == 0 ? QSCALE : 1.0f;
#pragma unroll
                    for (int r = 0; r < 4; r++) {
                        int row = mf * 16 + hi * 4 + r;
                        smem[row * 200 + col] = (_Float16)(acc[mf][nf][r] * sc);
                    }
                }
        }
        __builtin_amdgcn_s_barrier();
#pragma unroll
        for (int it = 0; it < 6; it++) {
            int c = it * 512 + tid;  // 3072 chunks = 128 rows x 24
            int row = c / 24, col8 = c - row * 24;
            int gm = bm + p * 128 + row;
            int gn = bn + col8 * 8;
            int tensor = gn >> 11;
            int ef = gn & 2047;
            int e = ef >> 7, f0 = ef & 127;
            uint4 v = *(const uint4*)&smem[row * 200 + col8 * 8];
            *(uint4*)(qkv + (size_t)tensor * (T_DIM * H_DIM) + (size_t)e * (T_DIM * DH) +
                      (size_t)gm * DH + f0) = v;
        }
    }
}

// =============== out-proj: 256x256 8-phase, split-K=4, fp16 partials =================
// Same proven ledger as round 6. NEW: LDS-repacked coalesced partial stores.
__global__ __launch_bounds__(512, 2) void oproj_kernel(const _Float16* __restrict__ A,
                                                       const _Float16* __restrict__ BT,
                                                       _Float16* __restrict__ part) {
    const int K = 2048, NT = 8;
    __shared__ _Float16 smem[65536];  // 128KB: A dbuf 2x16384 | B dbuf 2x16384
    _Float16* sA0 = smem;
    _Float16* sA1 = smem + 16384;
    _Float16* sB0 = smem + 32768;
    _Float16* sB1 = smem + 49152;

    int tid = threadIdx.x;
    int lane = tid & 63, wave = tid >> 6;
    int wm = wave >> 2, wn = wave & 3;
    int cb = lane & 15, hi = lane >> 4;

    int bid = blockIdx.x;
    int s = bid & 3, tile = bid >> 2;
    int by = tile >> 3, bx = tile & 7;
    int bm = by * 256, bn = bx * 256;
    int kbase = s * 512;

    f32x4 acc[8][4];
#pragma unroll
    for (int m = 0; m < 8; m++)
#pragma unroll
        for (int n = 0; n < 4; n++) acc[m][n] = (f32x4){0.f, 0.f, 0.f, 0.f};

    auto stageP = [&](int t, int p) {
        int buf = t & 1, k0 = kbase + (t << 6);
        const _Float16* src = (p < 2) ? A + (size_t)(bm + ((p & 1) << 7)) * K + k0
                                      : BT + (size_t)(bn + ((p & 1) << 7)) * K + k0;
        _Float16* dst = ((p < 2) ? (buf ? sA1 : sA0) : (buf ? sB1 : sB0)) + ((p & 1) << 13);
#pragma unroll
        for (int l = 0; l < 2; l++) {
            int c = l * 512 + tid;
            int rp = c >> 3, cc = c & 7;
            int col = (cc ^ (rp & 7)) << 3;
            gl_lds16(src + (size_t)rp * K + col, dst + c * 8);
        }
    };

    f16x8 a_lo[4][2], a_hi[4][2], b_lo[2][2], b_hi[2][2];

    stageP(0, 0); stageP(0, 1); stageP(0, 2); stageP(0, 3);
    stageP(1, 0); stageP(1, 1);
    asm volatile("s_waitcnt vmcnt(4)" ::: "memory");
    __builtin_amdgcn_s_barrier();

    for (int t = 0; t < NT; t++) {
        int buf = t & 1;
        const char* bA = (const char*)(buf ? sA1 : sA0);
        const char* bB = (const char*)(buf ? sB1 : sB0);
        // ph0
#pragma unroll
        for (int m = 0; m < 4; m++) {
            int ra = wm * 128 + m * 16 + cb;
#pragma unroll
            for (int ks = 0; ks < 2; ks++)
                a_lo[m][ks] = *(const f16x8*)(bA + (ra << 7) +
                                              ((ks * 64 + hi * 16) ^ ((ra & 7) << 4)));
        }
#pragma unroll
        for (int n = 0; n < 2; n++) {
            int rb = wn * 64 + n * 16 + cb;
#pragma unroll
            for (int ks = 0; ks < 2; ks++)
                b_lo[n][ks] = *(const f16x8*)(bB + (rb << 7) +
                                              ((ks * 64 + hi * 16) ^ ((rb & 7) << 4)));
        }
        if (t + 1 < NT) stageP(t + 1, 2);
        __builtin_amdgcn_s_barrier();
        asm volatile("s_waitcnt lgkmcnt(0)" ::: "memory");
        __builtin_amdgcn_s_setprio(1);
#pragma unroll
        for (int m = 0; m < 4; m++)
#pragma unroll
            for (int n = 0; n < 2; n++)
#pragma unroll
                for (int ks = 0; ks < 2; ks++)
                    acc[m][n] = __builtin_amdgcn_mfma_f32_16x16x32_f16(a_lo[m][ks], b_lo[n][ks], acc[m][n], 0, 0, 0);
        __builtin_amdgcn_s_setprio(0);
        __builtin_amdgcn_s_barrier();

        // ph1
#pragma unroll
        for (int m = 0; m < 4; m++) {
            int ra = wm * 128 + 64 + m * 16 + cb;
#pragma unroll
            for (int ks = 0; ks < 2; ks++)
                a_hi[m][ks] = *(const f16x8*)(bA + (ra << 7) +
                                              ((ks * 64 + hi * 16) ^ ((ra & 7) << 4)));
        }
#pragma unroll
        for (int n = 0; n < 2; n++) {
            int rb = wn * 64 + 32 + n * 16 + cb;
#pragma unroll
            for (int ks = 0; ks < 2; ks++)
                b_hi[n][ks] = *(const f16x8*)(bB + (rb << 7) +
                                              ((ks * 64 + hi * 16) ^ ((rb & 7) << 4)));
        }
        if (t + 1 < NT) stageP(t + 1, 3);
        __builtin_amdgcn_s_barrier();
        asm volatile("s_waitcnt lgkmcnt(0)" ::: "memory");
        __builtin_amdgcn_s_setprio(1);
#pragma unroll
        for (int m = 0; m < 4; m++)
#pragma unroll
            for (int n = 0; n < 2; n++)
#pragma unroll
                for (int ks = 0; ks < 2; ks++)
                    acc[4 + m][2 + n] = __builtin_amdgcn_mfma_f32_16x16x32_f16(a_hi[m][ks], b_hi[n][ks], acc[4 + m][2 + n], 0, 0, 0);
        __builtin_amdgcn_s_setprio(0);
        __builtin_amdgcn_s_barrier();

        // ph2
        if (t + 2 < NT) stageP(t + 2, 0);
        __builtin_amdgcn_s_barrier();
        __builtin_amdgcn_s_setprio(1);
#pragma unroll
        for (int m = 0; m < 4; m++)
#pragma unroll
            for (int n = 0; n < 2; n++)
#pragma unroll
                for (int ks = 0; ks < 2; ks++)
                    acc[m][2 + n] = __builtin_amdgcn_mfma_f32_16x16x32_f16(a_lo[m][ks], b_hi[n][ks], acc[m][2 + n], 0, 0, 0);
        __builtin_amdgcn_s_setprio(0);
        __builtin_amdgcn_s_barrier();

        // ph3
        if (t + 2 < NT) stageP(t + 2, 1);
        if (t < NT - 2)
            asm volatile("s_waitcnt vmcnt(4)" ::: "memory");
        else if (t == NT - 2)
            asm volatile("s_waitcnt vmcnt(0)" ::: "memory");
        __builtin_amdgcn_s_barrier();
        __builtin_amdgcn_s_setprio(1);
#pragma unroll
        for (int m = 0; m < 4; m++)
#pragma unroll
            for (int n = 0; n < 2; n++)
#pragma unroll
                for (int ks = 0; ks < 2; ks++)
                    acc[4 + m][n] = __builtin_amdgcn_mfma_f32_16x16x32_f16(a_hi[m][ks], b_lo[n][ks], acc[4 + m][n], 0, 0, 0);
        __builtin_amdgcn_s_setprio(0);
        __builtin_amdgcn_s_barrier();
    }

    // ---- epilogue: LDS repack (two 128-row passes, [128][264]) -> uint4 stores ----
    _Float16* pb = part + (size_t)s * T_DIM * H_DIM;
#pragma unroll
    for (int p = 0; p < 2; p++) {
        if (p) __builtin_amdgcn_s_barrier();
        if (wm == p) {
#pragma unroll
            for (int m = 0; m < 8; m++)
#pragma unroll
                for (int n = 0; n < 4; n++) {
                    int col = wn * 64 + ((n & 1) * 16) + ((n >> 1) * 32) + cb;
#pragma unroll
                    for (int r = 0; r < 4; r++) {
                        int row = ((m & 3) * 16) + ((m >> 2) * 64) + hi * 4 + r;
                        smem[row * 264 + col] = (_Float16)acc[m][n][r];
                    }
                }
        }
        __builtin_amdgcn_s_barrier();
#pragma unroll
        for (int it = 0; it < 8; it++) {
            int c = it * 512 + tid;  // 4096 chunks = 128 rows x 32
            int row = c >> 5, col8 = c & 31;
            int gm = bm + p * 128 + row;
            int gn = bn + col8 * 8;
            uint4 v = *(const uint4*)&smem[row * 264 + col8 * 8];
            *(uint4*)&pb[(size_t)gm * H_DIM + gn] = v;
        }
    }
}

// ---------------- reduce 4 fp16 partials -> fp32 out ----------------
__global__ __launch_bounds__(256) void reduce4_kernel(const _Float16* __restrict__ part,
                                                      float* __restrict__ out) {
    const size_t S = (size_t)T_DIM * H_DIM;
    int i = (blockIdx.x * 256 + threadIdx.x) * 8;
    f16x8 p0 = *(const f16x8*)&part[i];
    f16x8 p1 = *(const f16x8*)&part[S + i];
    f16x8 p2 = *(const f16x8*)&part[2 * S + i];
    f16x8 p3 = *(const f16x8*)&part[3 * S + i];
#pragma unroll
    for (int j = 0; j < 8; j++)
        out[i + j] = (float)p0[j] + (float)p1[j] + (float)p2[j] + (float)p3[j];
}

// ---------------- per-(block,head) attention ----------------
__global__ __launch_bounds__(256) void attn_kernel(const _Float16* __restrict__ qkvb,
                                                   const float* __restrict__ bias,
                                                   const float* __restrict__ mask,
                                                   _Float16* __restrict__ aout) {
    int bid = blockIdx.x;
    int n = bid >> 4, e = bid & 15;
    int t0 = n * KBLK;
    int valid = (T_DIM - t0 < KBLK) ? (T_DIM - t0) : KBLK;

    __shared__ _Float16 Qs[64 * 136];
    __shared__ _Float16 Ks[64 * 136];
    __shared__ _Float16 VTs[128 * 72];
    __shared__ _Float16 Ps[64 * 72];
    __shared__ float maskv[64];

    int tid = threadIdx.x;
    int lane = tid & 63, wave = tid >> 6;
    const _Float16* qp = qkvb + (size_t)e * (T_DIM * DH);
    const _Float16* kp = qkvb + (size_t)(T_DIM * H_DIM) + (size_t)e * (T_DIM * DH);
    const _Float16* vp = qkvb + (size_t)2 * (T_DIM * H_DIM) + (size_t)e * (T_DIM * DH);

#pragma unroll
    for (int i = 0; i < 4; i++) {
        int c = tid + i * 256;
        int r = c >> 4, c8 = c & 15;
        uint4 z = {0u, 0u, 0u, 0u};
        uint4 vq = z, vk = z;
        if (r < valid) {
            vq = *(const uint4*)&qp[(size_t)(t0 + r) * DH + c8 * 8];
            vk = *(const uint4*)&kp[(size_t)(t0 + r) * DH + c8 * 8];
        }
        *(uint4*)&Qs[r * 136 + c8 * 8] = vq;
        *(uint4*)&Ks[r * 136 + c8 * 8] = vk;
    }
#pragma unroll
    for (int i = 0; i < 4; i++) {
        int c = tid + i * 256;
        int r = c & 63;
        int f0 = (c >> 6) * 8;
        uint4 v = {0u, 0u, 0u, 0u};
        if (r < valid) v = *(const uint4*)&vp[(size_t)(t0 + r) * DH + f0];
        _Float16 tmp[8];
        *(uint4*)tmp = v;
#pragma unroll
        for (int j = 0; j < 8; j++) VTs[(f0 + j) * 72 + r] = tmp[j];
    }
    if (tid < 64) maskv[tid] = (tid < valid) ? mask[t0 + tid] : NEGV;
    __syncthreads();

    int qr0 = wave * 16;
    int cb = lane & 15, hi = lane >> 4;

    f16x8 aq[4];
#pragma unroll
    for (int ks = 0; ks < 4; ks++)
        aq[ks] = *(const f16x8*)&Qs[(qr0 + cb) * 136 + ks * 32 + hi * 8];
    f32x4 s[4];
#pragma unroll
    for (int kt = 0; kt < 4; kt++) s[kt] = (f32x4){0.f, 0.f, 0.f, 0.f};
#pragma unroll
    for (int kt = 0; kt < 4; kt++)
#pragma unroll
        for (int ks = 0; ks < 4; ks++) {
            f16x8 bk = *(const f16x8*)&Ks[(kt * 16 + cb) * 136 + ks * 32 + hi * 8];
            s[kt] = __builtin_amdgcn_mfma_f32_16x16x32_f16(aq[ks], bk, s[kt], 0, 0, 0);
        }

#pragma unroll
    for (int r = 0; r < 4; r++) {
        int rl = qr0 + hi * 4 + r;
        int qi = t0 + rl;
        float mq = maskv[rl];
        float lg[4];
        float mx = -3.4e38f;
#pragma unroll
        for (int kt = 0; kt < 4; kt++) {
            int cl = kt * 16 + cb, ki = t0 + cl;
            float bg = (qi < T_DIM && ki < T_DIM)
                           ? bias[((size_t)e * T_DIM + qi) * T_DIM + ki] : 0.f;
            float pr = mq * maskv[cl];
            float v = s[kt][r] + bg + (pr > 0.f ? 0.f : NEGV);
            lg[kt] = v;
            mx = fmaxf(mx, v);
        }
#pragma unroll
        for (int off = 8; off; off >>= 1) mx = fmaxf(mx, __shfl_xor(mx, off));
        float sum = 0.f;
#pragma unroll
        for (int kt = 0; kt < 4; kt++) {
            float pe = __expf(lg[kt] - mx);
            lg[kt] = pe;
            sum += pe;
        }
#pragma unroll
        for (int off = 8; off; off >>= 1) sum += __shfl_xor(sum, off);
        float inv = 1.f / sum;
#pragma unroll
        for (int kt = 0; kt < 4; kt++)
            Ps[rl * 72 + kt * 16 + cb] = (_Float16)(lg[kt] * inv);
    }
    __syncthreads();

    f16x8 pa[2];
#pragma unroll
    for (int ks = 0; ks < 2; ks++)
        pa[ks] = *(const f16x8*)&Ps[(qr0 + cb) * 72 + ks * 32 + hi * 8];
#pragma unroll
    for (int ft = 0; ft < 8; ft++) {
        f32x4 o = (f32x4){0.f, 0.f, 0.f, 0.f};
#pragma unroll
        for (int ks = 0; ks < 2; ks++) {
            f16x8 bv = *(const f16x8*)&VTs[(ft * 16 + cb) * 72 + ks * 32 + hi * 8];
            o = __builtin_amdgcn_mfma_f32_16x16x32_f16(pa[ks], bv, o, 0, 0, 0);
        }
#pragma unroll
        for (int r = 0; r < 4; r++) {
            int rl = qr0 + hi * 4 + r;
            if (rl < valid)
                aout[(size_t)(t0 + rl) * H_DIM + e * DH + ft * 16 + cb] = (_Float16)o[r];
        }
    }
}

extern "C" void kernel_launch(void* const* d_in, const int* in_sizes, int n_in,
                              void* d_out, int out_size, void* d_ws, size_t ws_size,
                              hipStream_t stream) {
    const float* x    = (const float*)d_in[0];
    const float* mask = (const float*)d_in[1];
    const float* bias = (const float*)d_in[2];
    const float* Wq   = (const float*)d_in[3];
    const float* Wk   = (const float*)d_in[4];
    const float* Wv   = (const float*)d_in[5];
    const float* Wo   = (const float*)d_in[6];
    float* out = (float*)d_out;

    // ws layout (f16): xb[4M] | WT[12M] | WoT[4M] | qkv[12M] | aout[4M] | part[16M] = 104MB
    _Float16* xb   = (_Float16*)d_ws;
    _Float16* WT   = xb + (size_t)T_DIM * H_DIM;
    _Float16* WoT  = WT + (size_t)3 * T_DIM * H_DIM;
    _Float16* qkvb = WoT + (size_t)T_DIM * H_DIM;
    _Float16* aout = qkvb + (size_t)3 * T_DIM * H_DIM;
    _Float16* part = aout + (size_t)T_DIM * H_DIM;

    prep_kernel<<<dim3(64, 64, 5), dim3(32, 8), 0, stream>>>(x, Wq, Wk, Wv, Wo, xb, WT, WoT);

    qkv192_kernel<<<256, 512, 0, stream>>>(xb, WT, qkvb);

    attn_kernel<<<NBLK * N_HEADS, 256, 0, stream>>>(qkvb, bias, mask, aout);

    oproj_kernel<<<256, 512, 0, stream>>>(aout, WoT, part);
    reduce4_kernel<<<(T_DIM * H_DIM) / (256 * 8), 256, 0, stream>>>(part, out);
}